// Round 7
// baseline (12612.502 us; speedup 1.0000x reference)
//
#include <hip/hip_runtime.h>

// ---------------------------------------------------------------------------
// V10: persistent MFMA LSTM — V8 protocol, HALF the workgroups (8 cols/WG).
//  Protocol (verified V4-V8): release = write-through h stores (sc0 sc1) ->
//  __syncthreads vmcnt drain -> per-WG relaxed flag store.  acquire = wave-0
//  polls flags (s_sleep throttled!) -> agent acquire fence (L1/L2 inv) ->
//  __syncthreads -> normal cached loads.  Skewed schedule (V5): iter i =
//  L0:h1(i), L1:h2(i-1).  h1 triple-buffered (V7): L0 slot guard = L1 >= i-1.
//
//  V9 post-mortem (reverted): sleep-free polling floods the MALL with bypass
//  loads and slows the exchange it waits on (9.27->11.85ms); hoisted x loads
//  get drained by the publish barrier.  V6-V8 proved forced load batching is
//  a null lever (sched fences removed again).
//
//  NEW vs V8: each WG owns 8 h-cols (2 MFMA n-tiles) -> NWG0=64, NWG1=32,
//  96 WGs total.  The sync chain is paced by agent count, not compute:
//  flag fan-in 192->96 (2 polled loads/lane), poll+exchange MALL traffic
//  halved, straggler population halved.  Compute per wave doubles (144 MFMA,
//  ~0.5us issue) — negligible.  wfa: 48 v4u; wfbs: 48 KB LDS.
// ---------------------------------------------------------------------------

constexpr int BB   = 64;
constexpr int TT   = 1024;
constexpr int DIN  = 256;
constexpr int H0   = 512;
constexpr int H1   = 256;
constexpr int NWG0 = 64;
constexpr int NWG1 = 32;
constexpr int NWG  = NWG0 + NWG1;
constexpr int NTHR = 256;
constexpr int NKT  = 24;       // K = 768 = 24 tiles of 32

typedef _Float16 v8h __attribute__((ext_vector_type(8)));
typedef __fp16   v2p __attribute__((ext_vector_type(2)));   // cvt_pkrtz result type
typedef float    v4f __attribute__((ext_vector_type(4)));
typedef unsigned int v4u __attribute__((ext_vector_type(4)));

union U1 { unsigned u; v2p h; };
union U4 { v4u u; v8h h; };

__device__ __forceinline__ unsigned pk2(float a, float b){
  U1 c; c.h = __builtin_amdgcn_cvt_pkrtz(a, b); return c.u;
}
__device__ __forceinline__ float lo16(unsigned u){ U1 c; c.u = u; return (float)c.h[0]; }
__device__ __forceinline__ float hi16(unsigned u){ U1 c; c.u = u; return (float)c.h[1]; }
__device__ __forceinline__ v8h as_h8(v4u u){ U4 c; c.u = u; return c.h; }

__device__ __forceinline__ v4f mfma16(v8h a, v8h b, v4f c){
  return __builtin_amdgcn_mfma_f32_16x16x32_f16(a, b, c, 0, 0, 0);
}

__device__ __forceinline__ float sigf(float v){ return 1.0f / (1.0f + __expf(-v)); }
__device__ __forceinline__ float tanhf_(float v){
  float e = __expf(2.0f * v);
  return 1.0f - 2.0f / (e + 1.0f);     // inf-safe
}

// wave-0 parallel flag wait (s_sleep throttled — V9 proved sleep-free polling
// congests the MALL).  Flags: flg[0..63] = L0 WGs (target tgt0),
// flg[64..95] = L1 WGs (target tgt1).  2 coalesced loads per lane.
__device__ __forceinline__ void waitflags2(const unsigned* f, unsigned tgt0,
                                           unsigned tgt1, int lane){
  const unsigned* p0 = f + lane;               // L0 flags, lanes 0..63
  const unsigned* p1 = f + 64 + (lane & 31);   // L1 flags (lanes >=32 duplicate)
  for (;;){
    bool ok = (__hip_atomic_load(p0, __ATOMIC_RELAXED, __HIP_MEMORY_SCOPE_AGENT) >= tgt0)
           && (__hip_atomic_load(p1, __ATOMIC_RELAXED, __HIP_MEMORY_SCOPE_AGENT) >= tgt1);
    if (__all(ok)) return;
    __builtin_amdgcn_s_sleep(1);
  }
}

// acquire at agent scope: s_waitcnt + invalidate L1/L2 so subsequent normal
// cached loads refill fresh data from the coherence point.
__device__ __forceinline__ void acq_fence(){
  __builtin_amdgcn_fence(__ATOMIC_ACQUIRE, "agent");
}

// pack two pair-dword quads into hi-plane / lo-plane A fragments
__device__ __forceinline__ void frag_from_pairs(v4u p0, v4u p1, v8h& A, v8h& B){
  v4u ua, ub;
  ua[0] = __builtin_amdgcn_perm(p0[1], p0[0], 0x05040100u);
  ua[1] = __builtin_amdgcn_perm(p0[3], p0[2], 0x05040100u);
  ua[2] = __builtin_amdgcn_perm(p1[1], p1[0], 0x05040100u);
  ua[3] = __builtin_amdgcn_perm(p1[3], p1[2], 0x05040100u);
  ub[0] = __builtin_amdgcn_perm(p0[1], p0[0], 0x07060302u);
  ub[1] = __builtin_amdgcn_perm(p0[3], p0[2], 0x07060302u);
  ub[2] = __builtin_amdgcn_perm(p1[1], p1[0], 0x07060302u);
  ub[3] = __builtin_amdgcn_perm(p1[3], p1[2], 0x07060302u);
  A = as_h8(ua); B = as_h8(ub);
}

__device__ __forceinline__ void frag_from_floats(v4f f0, v4f f1, v8h& A, v8h& B){
  float v[8] = { f0[0], f0[1], f0[2], f0[3], f1[0], f1[1], f1[2], f1[3] };
  v4u ua, ub;
  #pragma unroll
  for (int d = 0; d < 4; ++d){
    unsigned p = pk2(v[2*d], v[2*d+1]);
    ua[d] = p;
    ub[d] = pk2(v[2*d] - lo16(p), v[2*d+1] - hi16(p));
  }
  A = as_h8(ua); B = as_h8(ub);
}

__global__ void __launch_bounds__(NTHR, 1)
lstm_mfma(const float* __restrict__ x, const unsigned* __restrict__ xp, int use_xp,
          const float* __restrict__ Wih0, const float* __restrict__ bih0,
          const float* __restrict__ Whh0, const float* __restrict__ bhh0,
          const float* __restrict__ Wih1, const float* __restrict__ bih1,
          const float* __restrict__ Whh1, const float* __restrict__ bhh1,
          unsigned* h1p, unsigned* h2p,
          unsigned* flg, float* out)
{
  __shared__ v4u wfbs[2 * NKT * 64];   // 48 KB: lo-plane weight B-frags (A,B tiles)

  const int tid   = threadIdx.x;
  const int wg    = blockIdx.x;
  const bool isL0 = wg < NWG0;
  const int lw    = isL0 ? wg : wg - NWG0;
  const int H     = isL0 ? H0 : H1;
  const int jbase = lw * 8;            // 8 h-cols per WG (two n-tiles of 4)
  const int lane  = tid & 63;
  const int mt    = tid >> 6;          // wave id = m-tile (16 batches)
  const int n     = lane & 15;         // MFMA n-index / A row-in-tile
  const int quad  = lane >> 4;
  // n -> gate (n>>2 in {i,f,g,o}); tile A h-col jbase+(n&3), tile B +4
  const int gcolA = (n >> 2) * H + jbase + (n & 3);
  const int gcolB = gcolA + 4;
  const int brow  = mt * 16 + n;       // batch row this lane loads for A

  // ---- prologue: weight B-fragments for both n-tiles; hi->VGPR, lo->LDS ----
  v4u wfaA[NKT], wfaB[NKT];
  {
    const float* Wi = isL0 ? Wih0 : Wih1;
    const float* Wh = isL0 ? Whh0 : Whh1;
    const int Ki  = isL0 ? DIN : H0;
    const int ldw = 4 * H;
    #pragma unroll
    for (int kt = 0; kt < NKT; ++kt){
      const int ks = kt * 32 + quad * 8;
      float wA[8], wB[8];
      #pragma unroll
      for (int j = 0; j < 8; ++j){
        const int k = ks + j;
        const float* Wrow = (k < Ki) ? (Wi + (size_t)k * ldw)
                                     : (Wh + (size_t)(k - Ki) * ldw);
        wA[j] = Wrow[gcolA];
        wB[j] = Wrow[gcolB];
      }
      v4u uaA, ubA, uaB, ubB;
      #pragma unroll
      for (int d = 0; d < 4; ++d){
        unsigned pA = pk2(wA[2*d], wA[2*d+1]);
        uaA[d] = pA;
        ubA[d] = pk2(wA[2*d] - lo16(pA), wA[2*d+1] - hi16(pA));
        unsigned pB = pk2(wB[2*d], wB[2*d+1]);
        uaB[d] = pB;
        ubB[d] = pk2(wB[2*d] - lo16(pB), wB[2*d+1] - hi16(pB));
      }
      wfaA[kt] = uaA; wfaB[kt] = uaB;
      if (mt == 0){
        wfbs[kt * 64 + lane] = ubA;            // identical across waves
        wfbs[(NKT + kt) * 64 + lane] = ubB;
      }
    }
  }
  const float bsumA = isL0 ? (bih0[gcolA] + bhh0[gcolA]) : (bih1[gcolA] + bhh1[gcolA]);
  const float bsumB = isL0 ? (bih0[gcolB] + bhh0[gcolB]) : (bih1[gcolB] + bhh1[gcolB]);

  // cell state for 8 cols (lanes n<4): A-tile c0..c3, B-tile c4..c7
  float cA0=0.f,cA1=0.f,cA2=0.f,cA3=0.f, cB0=0.f,cB1=0.f,cB2=0.f,cB3=0.f;
  __syncthreads();

  // iteration i: L0 computes h1(i) (for i < TT); L1 computes h2(i-1) (i >= 1)
  for (int i = 0; i <= TT; ++i){
    const bool act = isL0 ? (i < TT) : (i >= 1);
    const int t    = isL0 ? i : (i - 1);          // this WG's time index
    const int s_w  = ((unsigned)t) % 3u;          // h1 write slot (L0)
    const int s_r  = ((unsigned)(t + 2)) % 3u;    // h1(t-1) read slot (L0)
    const int s_c  = ((unsigned)t) % 3u;          // h1(t) read slot (L1)

    v4f acc1A = { bsumA, bsumA, bsumA, bsumA };
    v4f acc2A = { 0.f, 0.f, 0.f, 0.f };
    v4f acc1B = { bsumB, bsumB, bsumB, bsumB };
    v4f acc2B = { 0.f, 0.f, 0.f, 0.f };

    // ---- L0 x-part: no cross-WG dependency, runs before the wait ----
    if (isL0 && act){
      if (use_xp){
        const unsigned* xr = xp + ((size_t)brow * TT + t) * DIN + quad * 8;
        #pragma unroll
        for (int kt = 0; kt < 8; ++kt){
          v4u p0 = *(const v4u*)(xr + kt * 32);
          v4u p1 = *(const v4u*)(xr + kt * 32 + 4);
          v8h A, Ab; frag_from_pairs(p0, p1, A, Ab);
          v8h WaA = as_h8(wfaA[kt]), WbA = as_h8(wfbs[kt * 64 + lane]);
          v8h WaB = as_h8(wfaB[kt]), WbB = as_h8(wfbs[(NKT + kt) * 64 + lane]);
          acc1A = mfma16(A,  WaA, acc1A);
          acc2A = mfma16(A,  WbA, acc2A);
          acc2A = mfma16(Ab, WaA, acc2A);
          acc1B = mfma16(A,  WaB, acc1B);
          acc2B = mfma16(A,  WbB, acc2B);
          acc2B = mfma16(Ab, WaB, acc2B);
        }
      } else {
        const float* xr = x + ((size_t)brow * TT + t) * DIN + quad * 8;
        #pragma unroll
        for (int kt = 0; kt < 8; ++kt){
          v4f f0 = *(const v4f*)(xr + kt * 32);
          v4f f1 = *(const v4f*)(xr + kt * 32 + 4);
          v8h A, Ab; frag_from_floats(f0, f1, A, Ab);
          v8h WaA = as_h8(wfaA[kt]), WbA = as_h8(wfbs[kt * 64 + lane]);
          v8h WaB = as_h8(wfaB[kt]), WbB = as_h8(wfbs[(NKT + kt) * 64 + lane]);
          acc1A = mfma16(A,  WaA, acc1A);
          acc2A = mfma16(A,  WbA, acc2A);
          acc2A = mfma16(Ab, WaA, acc2A);
          acc1B = mfma16(A,  WaB, acc1B);
          acc2B = mfma16(A,  WbB, acc2B);
          acc2B = mfma16(Ab, WaB, acc2B);
        }
      }
    }

    // ---- per-iteration sync.  L0: L0 flags >= i, L1 flags >= i-1 (3-slot
    //      guard).  L1: all flags >= i (true dep on h1(i-1), h2(i-2)). ----
    if (tid < 64){
      if (i >= 1){
        if (isL0) waitflags2(flg, (unsigned)i, (i >= 2) ? (unsigned)(i - 1) : 0u, lane);
        else      waitflags2(flg, (unsigned)i, (unsigned)i, lane);
      }
      acq_fence();          // unconditional: also guards graph-replay staleness
    }
    __syncthreads();

    if (act){
      if (isL0){
        // ---- h1(t-1) part, slot s_r ----
        const unsigned* hr = h1p + (size_t)s_r * (BB * H0)
                                 + (size_t)brow * H0 + quad * 8;
        #pragma unroll
        for (int kt = 0; kt < 16; ++kt){
          v4u p0 = *(const v4u*)(hr + kt * 32);
          v4u p1 = *(const v4u*)(hr + kt * 32 + 4);
          v8h A, Ab; frag_from_pairs(p0, p1, A, Ab);
          v8h WaA = as_h8(wfaA[kt + 8]), WbA = as_h8(wfbs[(kt + 8) * 64 + lane]);
          v8h WaB = as_h8(wfaB[kt + 8]), WbB = as_h8(wfbs[(NKT + kt + 8) * 64 + lane]);
          acc1A = mfma16(A,  WaA, acc1A);
          acc2A = mfma16(A,  WbA, acc2A);
          acc2A = mfma16(Ab, WaA, acc2A);
          acc1B = mfma16(A,  WaB, acc1B);
          acc2B = mfma16(A,  WbB, acc2B);
          acc2B = mfma16(Ab, WaB, acc2B);
        }
      } else {
        // ---- L1: h2(t-1) part then h1(t) part ----
        const unsigned* h2r = h2p + (size_t)((t + 1) & 1) * (BB * H1)
                                  + (size_t)brow * H1 + quad * 8;
        #pragma unroll
        for (int kt = 0; kt < 8; ++kt){
          v4u p0 = *(const v4u*)(h2r + kt * 32);
          v4u p1 = *(const v4u*)(h2r + kt * 32 + 4);
          v8h A, Ab; frag_from_pairs(p0, p1, A, Ab);
          v8h WaA = as_h8(wfaA[kt + 16]), WbA = as_h8(wfbs[(kt + 16) * 64 + lane]);
          v8h WaB = as_h8(wfaB[kt + 16]), WbB = as_h8(wfbs[(NKT + kt + 16) * 64 + lane]);
          acc1A = mfma16(A,  WaA, acc1A);
          acc2A = mfma16(A,  WbA, acc2A);
          acc2A = mfma16(Ab, WaA, acc2A);
          acc1B = mfma16(A,  WaB, acc1B);
          acc2B = mfma16(A,  WbB, acc2B);
          acc2B = mfma16(Ab, WaB, acc2B);
        }
        const unsigned* hr = h1p + (size_t)s_c * (BB * H0)
                                 + (size_t)brow * H0 + quad * 8;
        #pragma unroll
        for (int kt = 0; kt < 16; ++kt){
          v4u p0 = *(const v4u*)(hr + kt * 32);
          v4u p1 = *(const v4u*)(hr + kt * 32 + 4);
          v8h A, Ab; frag_from_pairs(p0, p1, A, Ab);
          v8h WaA = as_h8(wfaA[kt]), WbA = as_h8(wfbs[kt * 64 + lane]);
          v8h WaB = as_h8(wfaB[kt]), WbB = as_h8(wfbs[(NKT + kt) * 64 + lane]);
          acc1A = mfma16(A,  WaA, acc1A);
          acc2A = mfma16(A,  WbA, acc2A);
          acc2A = mfma16(Ab, WaA, acc2A);
          acc1B = mfma16(A,  WaB, acc1B);
          acc2B = mfma16(A,  WbB, acc2B);
          acc2B = mfma16(Ab, WaB, acc2B);
        }
      }

      // ---- elementwise LSTM for both n-tiles via shfl_xor gather ----
      v4f gvA = acc1A + acc2A;
      v4f gvB = acc1B + acc2B;
      float pA0 = __shfl_xor(gvA[0], 4), pA1 = __shfl_xor(gvA[1], 4),
            pA2 = __shfl_xor(gvA[2], 4), pA3 = __shfl_xor(gvA[3], 4);
      float qA0 = __shfl_xor(gvA[0], 8), qA1 = __shfl_xor(gvA[1], 8),
            qA2 = __shfl_xor(gvA[2], 8), qA3 = __shfl_xor(gvA[3], 8);
      float sA0 = __shfl_xor(pA0, 8), sA1 = __shfl_xor(pA1, 8),
            sA2 = __shfl_xor(pA2, 8), sA3 = __shfl_xor(pA3, 8);
      float pB0 = __shfl_xor(gvB[0], 4), pB1 = __shfl_xor(gvB[1], 4),
            pB2 = __shfl_xor(gvB[2], 4), pB3 = __shfl_xor(gvB[3], 4);
      float qB0 = __shfl_xor(gvB[0], 8), qB1 = __shfl_xor(gvB[1], 8),
            qB2 = __shfl_xor(gvB[2], 8), qB3 = __shfl_xor(gvB[3], 8);
      float sB0 = __shfl_xor(pB0, 8), sB1 = __shfl_xor(pB1, 8),
            sB2 = __shfl_xor(pB2, 8), sB3 = __shfl_xor(pB3, 8);

      if (n < 4){
        float ivA[4] = { gvA[0], gvA[1], gvA[2], gvA[3] };
        float fvA[4] = { pA0, pA1, pA2, pA3 };
        float ggA[4] = { qA0, qA1, qA2, qA3 };
        float ovA[4] = { sA0, sA1, sA2, sA3 };
        float ivB[4] = { gvB[0], gvB[1], gvB[2], gvB[3] };
        float fvB[4] = { pB0, pB1, pB2, pB3 };
        float ggB[4] = { qB0, qB1, qB2, qB3 };
        float ovB[4] = { sB0, sB1, sB2, sB3 };
        float ccA[4] = { cA0, cA1, cA2, cA3 };
        float ccB[4] = { cB0, cB1, cB2, cB3 };
        const int colA = jbase + n;
        const int colB = colA + 4;
        #pragma unroll
        for (int r = 0; r < 4; ++r){
          const int b = mt * 16 + quad * 4 + r;
          float cnA = sigf(fvA[r]) * ccA[r] + sigf(ivA[r]) * tanhf_(ggA[r]);
          float hnA = sigf(ovA[r]) * tanhf_(cnA);
          ccA[r] = cnA;
          float cnB = sigf(fvB[r]) * ccB[r] + sigf(ivB[r]) * tanhf_(ggB[r]);
          float hnB = sigf(ovB[r]) * tanhf_(cnB);
          ccB[r] = cnB;
          unsigned paA = pk2(hnA, 0.f);
          unsigned pdA = pk2(hnA, hnA - lo16(paA));
          unsigned paB = pk2(hnB, 0.f);
          unsigned pdB = pk2(hnB, hnB - lo16(paB));
          if (isL0){
            unsigned* hb = h1p + (size_t)s_w * (BB * H0) + (size_t)b * H0;
            __hip_atomic_store(hb + colA, pdA, __ATOMIC_RELAXED, __HIP_MEMORY_SCOPE_AGENT);
            __hip_atomic_store(hb + colB, pdB, __ATOMIC_RELAXED, __HIP_MEMORY_SCOPE_AGENT);
          } else {
            unsigned* hb = h2p + (size_t)(t & 1) * (BB * H1) + (size_t)b * H1;
            __hip_atomic_store(hb + colA, pdA, __ATOMIC_RELAXED, __HIP_MEMORY_SCOPE_AGENT);
            __hip_atomic_store(hb + colB, pdB, __ATOMIC_RELAXED, __HIP_MEMORY_SCOPE_AGENT);
            float* ob = out + ((size_t)b * TT + t) * H1;
            // write-through so per-step L2 invalidates never see a dirty line
            __hip_atomic_store(ob + colA, hnA, __ATOMIC_RELAXED, __HIP_MEMORY_SCOPE_AGENT);
            __hip_atomic_store(ob + colB, hnB, __ATOMIC_RELAXED, __HIP_MEMORY_SCOPE_AGENT);
          }
        }
        cA0=ccA[0]; cA1=ccA[1]; cA2=ccA[2]; cA3=ccA[3];
        cB0=ccB[0]; cB1=ccB[1]; cB2=ccB[2]; cB3=ccB[3];
      }
    }

    // ---- publish: barrier drains vmcnt (write-through stores are at the
    // coherence point once retired) -> per-WG relaxed flag store suffices ----
    __syncthreads();
    if (tid == 0){
      __hip_atomic_store(flg + wg, (unsigned)(i + 1),
                         __ATOMIC_RELAXED, __HIP_MEMORY_SCOPE_AGENT);
    }
  }
}

__global__ void init_ws(unsigned* ws, int nz){
  int i = blockIdx.x * blockDim.x + threadIdx.x;
  if (i < nz)
    __hip_atomic_store(ws + i, 0u, __ATOMIC_RELAXED, __HIP_MEMORY_SCOPE_AGENT);
}

__global__ void conv_x(const float4* __restrict__ x4,
                       unsigned long long* __restrict__ xp2, int n4){
  int i = blockIdx.x * blockDim.x + threadIdx.x;
  if (i >= n4) return;
  float4 f = x4[i];
  float v[4] = { f.x, f.y, f.z, f.w };
  unsigned o[4];
  #pragma unroll
  for (int d = 0; d < 4; ++d){
    unsigned p = pk2(v[d], 0.f);
    o[d] = pk2(v[d], v[d] - lo16(p));
  }
  unsigned long long lo = (unsigned long long)o[0] | ((unsigned long long)o[1] << 32);
  unsigned long long hi = (unsigned long long)o[2] | ((unsigned long long)o[3] << 32);
  // write-through: no dirty L2 lines to be lost by lstm_mfma's invalidates
  __hip_atomic_store(xp2 + 2 * i + 0, lo, __ATOMIC_RELAXED, __HIP_MEMORY_SCOPE_AGENT);
  __hip_atomic_store(xp2 + 2 * i + 1, hi, __ATOMIC_RELAXED, __HIP_MEMORY_SCOPE_AGENT);
}

extern "C" void kernel_launch(void* const* d_in, const int* in_sizes, int n_in,
                              void* d_out, int out_size, void* d_ws, size_t ws_size,
                              hipStream_t stream) {
  const float* x    = (const float*)d_in[0];
  const float* Wih0 = (const float*)d_in[1];
  const float* bih0 = (const float*)d_in[2];
  const float* Whh0 = (const float*)d_in[3];
  const float* bhh0 = (const float*)d_in[4];
  const float* Wih1 = (const float*)d_in[5];
  const float* bih1 = (const float*)d_in[6];
  const float* Whh1 = (const float*)d_in[7];
  const float* bhh1 = (const float*)d_in[8];
  float* outp = (float*)d_out;

  unsigned* ws   = (unsigned*)d_ws;
  unsigned* h1p  = ws;                       // 3*64*512  = 98304 dwords (3 slots)
  unsigned* h2p  = h1p + 3 * BB * H0;        // 2*64*256  = 32768
  unsigned* flg  = h2p + 2 * BB * H1;        // region sized 2*TT dwords (uses 96)
  unsigned* xp   = flg + 2 * TT;             // optional: B*T*DIN pair dwords
  const int nz = 3 * BB * H0 + 2 * BB * H1 + 2 * TT;   // dwords to zero

  const size_t need_xp = ((size_t)nz + (size_t)BB * TT * DIN) * 4;
  int use_xp = (ws_size >= need_xp) ? 1 : 0;

  init_ws<<<dim3((nz + 255) / 256), dim3(256), 0, stream>>>(ws, nz);
  if (use_xp){
    const int n4 = BB * TT * DIN / 4;
    conv_x<<<dim3((n4 + 255) / 256), dim3(256), 0, stream>>>(
        (const float4*)x, (unsigned long long*)xp, n4);
  }

  lstm_mfma<<<dim3(NWG), dim3(NTHR), 0, stream>>>(
      x, xp, use_xp,
      Wih0, bih0, Whh0, bhh0,
      Wih1, bih1, Whh1, bhh1,
      h1p, h2p, flg, outp);
}